// Round 1
// baseline (998.333 us; speedup 1.0000x reference)
//
#include <hip/hip_runtime.h>

// GCN_88734024335852 — 2-layer GCN on MI355X
//
// R12: replace the two-level bucket sort (k_sortplace 79us + k_csr2) with a
// plain global counting sort. Rationale: sortplace was latency/sync-bound
// (16% HBM, 12% VALU, 0 MFMA) on histogram/scan/staging machinery, and csr2
// re-read + re-scattered the whole edge list. Counting sort needs only
// 12.8M scattered L2 atomics total (deg + cursor), which is cheap: agg16g
// already sustains 51M scattered L2 gathers in <78us. CSR region ORDER
// across nodes is irrelevant (sums commute), so the scan is per-block with
// one global atomic region-claim -> no global dependency chain.
//
//   dinv[i] = rsqrt(deg_in[i]+1)
//   layer out[c] = dinv[c] * ( g[c] + sum_{col[e]==c} g[row[e]] ) + b
//   g[i] = (h[i] @ W) * dinv[i]
//
// ws (floats): xe[n] dinv[n] g[16n] g2[n] gbuf[8n] uptr[2n] cur[n] deg[n]
//              gtotal[16] eb2[ne]   (~38 MB)

#define D_FEAT 128
#define HIDDEN 16

__device__ inline float bf2f(unsigned short u) {
    union { unsigned x; float f; } t; t.x = ((unsigned)u) << 16; return t.f;
}

__global__ __launch_bounds__(256) void k_init(float* xe, unsigned* deg, unsigned* gtotal, int n) {
    int t = blockIdx.x * 256 + threadIdx.x;
    if (t < n) { xe[t] = 0.f; deg[t] = 0u; }
    if (t == 0) gtotal[0] = 0u;
}

// In-degree count: 8 edges/thread via 2x int4, scattered global atomics.
__global__ __launch_bounds__(256) void k_deg(const int* __restrict__ col,
                                             unsigned* __restrict__ deg, int ne) {
    int t = blockIdx.x * 256 + threadIdx.x;
    int e0 = t * 8;
    if (e0 + 7 < ne) {
        int4 c0 = *(const int4*)&col[e0];
        int4 c1 = *(const int4*)&col[e0 + 4];
        atomicAdd(&deg[c0.x], 1u); atomicAdd(&deg[c0.y], 1u);
        atomicAdd(&deg[c0.z], 1u); atomicAdd(&deg[c0.w], 1u);
        atomicAdd(&deg[c1.x], 1u); atomicAdd(&deg[c1.y], 1u);
        atomicAdd(&deg[c1.z], 1u); atomicAdd(&deg[c1.w], 1u);
    } else {
        for (int e = e0; e < ne; ++e) atomicAdd(&deg[col[e]], 1u);
    }
}

// Per-block exclusive scan of deg (256 nodes) + one global region claim.
// Region order across blocks is arbitrary -> no global scan needed.
__global__ __launch_bounds__(256) void k_scan(const unsigned* __restrict__ deg,
                                              uint2* __restrict__ uptr,
                                              unsigned* __restrict__ cur,
                                              float* __restrict__ dinv,
                                              unsigned* __restrict__ gtotal, int n) {
    __shared__ unsigned sc[256];
    __shared__ unsigned sbase;
    int tid = threadIdx.x;
    int v = blockIdx.x * 256 + tid;
    unsigned d = (v < n) ? deg[v] : 0u;
    sc[tid] = d;
    __syncthreads();
    for (int off = 1; off < 256; off <<= 1) {
        unsigned u = (tid >= off) ? sc[tid - off] : 0u;
        __syncthreads();
        sc[tid] += u;
        __syncthreads();
    }
    if (tid == 255) sbase = atomicAdd(gtotal, sc[255]);
    __syncthreads();
    if (v < n) {
        unsigned ex = sbase + sc[tid] - d;
        uptr[v] = make_uint2(ex, ex + d);
        cur[v] = ex;
        dinv[v] = rsqrtf((float)d + 1.0f);
    }
}

// Scatter edges into col-CSR via atomic cursor; fused xe segmented scan
// (rows sorted globally -> per-64-edge-wave-window scan + tail atomic).
__global__ __launch_bounds__(256) void k_scatter(const int* __restrict__ row,
                                                 const int* __restrict__ col,
                                                 const float* __restrict__ ea,
                                                 float* __restrict__ xe,
                                                 unsigned* __restrict__ cur,
                                                 unsigned* __restrict__ eb2,
                                                 int ne) {
    int tid = threadIdx.x;
    int lane = tid & 63;
    int tile0 = blockIdx.x * 2048;
    int rr[8], cc[8];
    float aa[8];
    #pragma unroll
    for (int k = 0; k < 8; ++k) {
        int e = tile0 + tid + k * 256;   // wave-contiguous 64-edge windows
        if (e < ne) {
            rr[k] = row[e]; cc[k] = col[e]; aa[k] = ea[e];
        } else { rr[k] = -1; cc[k] = 0; aa[k] = 0.f; }
    }
    // xe segmented scan per 64-edge wave window (rows sorted globally).
    #pragma unroll
    for (int k = 0; k < 8; ++k) {
        int r = rr[k];
        float a = aa[k];
        #pragma unroll
        for (int d = 1; d < 64; d <<= 1) {
            float up = __shfl_up(a, d);
            int  rup = __shfl_up(r, d);
            if (lane >= d && rup == r) a += up;
        }
        int rdn = __shfl_down(r, 1);
        bool tail = (lane == 63) || (rdn != r);
        if (r >= 0 && tail) unsafeAtomicAdd(&xe[r], a);
    }
    // Claim slots (8-deep ILP on atomic round-trips), then scatter rows.
    unsigned pos[8];
    #pragma unroll
    for (int k = 0; k < 8; ++k)
        if (rr[k] >= 0) pos[k] = atomicAdd(&cur[cc[k]], 1u);
    #pragma unroll
    for (int k = 0; k < 8; ++k)
        if (rr[k] >= 0) eb2[pos[k]] = (unsigned)rr[k];
}

// g[i][j] = (sum_k x[i][k]*W1[k][j] + xe[i]*W1[128][j]) * dinv[i]
// W transposed in LDS (stride 132) -> b128 weight reads.
// Writes fp32 g (self-term) and bf16 gbuf (gather copy, RNE).
__global__ __launch_bounds__(256) void k_gemm1(const float* __restrict__ x,
                                               const float* __restrict__ xe,
                                               const float* __restrict__ dinv,
                                               const float* __restrict__ W1,
                                               float* __restrict__ g,
                                               unsigned short* __restrict__ gb, int n) {
    __shared__ float WsT[16 * 132];   // WsT[j*132 + k] = W1[k*16 + j], k=0..128
    __shared__ float xs[64 * 132];
    int tid = threadIdx.x;
    for (int idx = tid; idx < 129 * 16; idx += 256) {
        int k = idx >> 4, j = idx & 15;
        WsT[j * 132 + k] = W1[idx];
    }
    int n0 = blockIdx.x * 64;
    const float4* x4 = (const float4*)x;
    for (int idx = tid; idx < 64 * 32; idx += 256) {
        int r = idx >> 5, c = idx & 31;
        float4 v = (n0 + r < n) ? x4[(size_t)(n0 + r) * 32 + c]
                                : make_float4(0.f, 0.f, 0.f, 0.f);
        *(float4*)&xs[r * 132 + c * 4] = v;
    }
    if (tid < 64) {
        int r = tid;
        xs[r * 132 + 128] = (n0 + r < n) ? xe[n0 + r] : 0.f;
    }
    __syncthreads();
    int j  = tid & 15;
    int nb = tid >> 4;
    const float* wrow = &WsT[j * 132];
    for (int rep = 0; rep < 4; ++rep) {
        int nl = nb + (rep << 4);
        int node = n0 + nl;
        const float* xrow = &xs[nl * 132];
        float acc = 0.f;
        #pragma unroll
        for (int k = 0; k < 128; k += 4) {
            float4 xv = *(const float4*)&xrow[k];
            float4 wv = *(const float4*)&wrow[k];
            acc += xv.x * wv.x;
            acc += xv.y * wv.y;
            acc += xv.z * wv.z;
            acc += xv.w * wv.w;
        }
        acc += xrow[128] * wrow[128];
        if (node < n) {
            float v = acc * dinv[node];
            g[(size_t)node * 16 + j] = v;
            union { float f; unsigned u; } cv; cv.f = v;
            unsigned r16 = (cv.u + 0x7FFFu + ((cv.u >> 16) & 1u)) >> 16;
            gb[(size_t)node * 16 + j] = (unsigned short)r16;
        }
    }
}

// Layer-1 agg, packed: 16 lanes/node; lane u=tid&7 owns feature pair
// (2u,2u+1) as one uint load; halves (tid>>3)&1 split even/odd edges;
// shfl_xor(8) combines. Fused epilogue. No LDS, no atomics.
__global__ __launch_bounds__(256) void k_agg16g(const uint2* __restrict__ uptr,
                                                const unsigned* __restrict__ eb2,
                                                const unsigned* __restrict__ gu,
                                                const float* __restrict__ g,
                                                const float* __restrict__ dinv,
                                                const float* __restrict__ b1,
                                                const float* __restrict__ W2,
                                                float* __restrict__ g2, int n) {
    int tid = threadIdx.x;
    int grp = tid >> 4, j16 = tid & 15;
    int u = tid & 7;
    int half = (tid >> 3) & 1;
    int v = blockIdx.x * 16 + grp;
    if (v >= n) return;
    uint2 pr = uptr[v];
    float ax0 = 0.f, ay0 = 0.f, ax1 = 0.f, ay1 = 0.f;
    unsigned q = pr.x + half;
    for (; q + 2 < pr.y; q += 4) {
        unsigned r0 = eb2[q], r1 = eb2[q + 2];
        unsigned w0 = gu[(size_t)r0 * 8 + u];
        unsigned w1 = gu[(size_t)r1 * 8 + u];
        ax0 += bf2f((unsigned short)w0); ay0 += bf2f((unsigned short)(w0 >> 16));
        ax1 += bf2f((unsigned short)w1); ay1 += bf2f((unsigned short)(w1 >> 16));
    }
    if (q < pr.y) {
        unsigned w = gu[(size_t)eb2[q] * 8 + u];
        ax0 += bf2f((unsigned short)w); ay0 += bf2f((unsigned short)(w >> 16));
    }
    float sx = ax0 + ax1, sy = ay0 + ay1;
    sx += __shfl_xor(sx, 8, 16);
    sy += __shfl_xor(sy, 8, 16);
    float di = dinv[v];
    float2 gs = ((const float2*)g)[(size_t)v * 8 + u];
    float2 bb = ((const float2*)b1)[u];
    float2 ww = ((const float2*)W2)[u];
    float vx = fmaxf(di * (gs.x + sx) + bb.x, 0.f);
    float vy = fmaxf(di * (gs.y + sy) + bb.y, 0.f);
    float prd = vx * ww.x + vy * ww.y;
    prd += __shfl_down(prd, 4, 8);
    prd += __shfl_down(prd, 2, 8);
    prd += __shfl_down(prd, 1, 8);
    if (j16 == 0) g2[v] = prd * di;
}

// Layer-2 agg as CSR segmented reduction + fused output.
__global__ __launch_bounds__(256) void k_agg1f(const uint2* __restrict__ uptr,
                                               const unsigned* __restrict__ eb2,
                                               const float* __restrict__ g2,
                                               const float* __restrict__ dinv,
                                               const float* __restrict__ b2,
                                               float* __restrict__ out, int n) {
    int tid = threadIdx.x;
    int grp = tid >> 4, j = tid & 15;
    int v = blockIdx.x * 16 + grp;
    if (v >= n) return;
    uint2 pr = uptr[v];
    float a = 0.f;
    for (unsigned i = pr.x + j; i < pr.y; i += 16) a += g2[eb2[i]];
    a += __shfl_down(a, 8, 16);
    a += __shfl_down(a, 4, 16);
    a += __shfl_down(a, 2, 16);
    a += __shfl_down(a, 1, 16);
    if (j == 0) out[v] = dinv[v] * (g2[v] + a) + b2[0];
}

extern "C" void kernel_launch(void* const* d_in, const int* in_sizes, int n_in,
                              void* d_out, int out_size, void* d_ws, size_t ws_size,
                              hipStream_t stream) {
    const float* x   = (const float*)d_in[0];
    const float* ea  = (const float*)d_in[1];
    const int*   row = (const int*)d_in[2];
    const int*   col = (const int*)d_in[3];
    const float* W1  = (const float*)d_in[4];
    const float* b1  = (const float*)d_in[5];
    const float* W2  = (const float*)d_in[6];
    const float* b2  = (const float*)d_in[7];
    float* out = (float*)d_out;

    int n  = in_sizes[0] / D_FEAT;   // 100000
    int ne = in_sizes[2];            // 6400000

    float* ws   = (float*)d_ws;
    float* xe   = ws;                      // n
    float* dinv = ws + (size_t)n;          // n
    float* g    = ws + (size_t)2 * n;      // 16n
    float* g2   = ws + (size_t)18 * n;     // n
    unsigned short* gbuf = (unsigned short*)(ws + (size_t)19 * n);  // 16n ushort = 8n floats
    uint2*    uptr   = (uint2*)(ws + (size_t)27 * n);      // n uint2 = 2n
    unsigned* cur    = (unsigned*)(ws + (size_t)29 * n);   // n
    unsigned* deg    = cur + (size_t)n;                    // n
    unsigned* gtotal = deg + (size_t)n;                    // 16 (padded)
    unsigned* eb2    = gtotal + 16;                        // ne

    dim3 blk(256);
    int g_node  = (n + 255) / 256;
    int g_edge8 = (ne + 2047) / 2048;
    int g_gemm  = (n + 63) / 64;
    int g_n16   = (n + 15) / 16;

    k_init<<<g_node, blk, 0, stream>>>(xe, deg, gtotal, n);
    k_deg<<<g_edge8, blk, 0, stream>>>(col, deg, ne);
    k_scan<<<g_node, blk, 0, stream>>>(deg, uptr, cur, dinv, gtotal, n);
    k_scatter<<<g_edge8, blk, 0, stream>>>(row, col, ea, xe, cur, eb2, ne);
    k_gemm1<<<g_gemm, blk, 0, stream>>>(x, xe, dinv, W1, g, gbuf, n);
    k_agg16g<<<g_n16, blk, 0, stream>>>(uptr, eb2, (const unsigned*)gbuf, g, dinv, b1, W2, g2, n);
    k_agg1f<<<g_n16, blk, 0, stream>>>(uptr, eb2, g2, dinv, b2, out, n);
}

// Round 2
// 345.223 us; speedup vs baseline: 2.8918x; 2.8918x over previous
//
#include <hip/hip_runtime.h>

// GCN_88734024335852 — 2-layer GCN on MI355X
//
// R13: revert R12's counting sort (scattered 4B CSR writes -> 394MB HBM
// write, 580us; the bucket-staged design's coalescing earned its cost).
// Back to R11's two-level bucket sort, with the latency fix R11's counters
// pointed at: sortplace was 16% HBM / 12% VALU / 0 MFMA -> sync-bound.
// Replace the 512-wide Hillis-Steele scan (18 barriers) with wave shfl
// scans + one cross-wave combine (2 barriers); same in csr2 (256 entries).
//
//   dinv[i] = rsqrt(deg_in[i]+1)
//   layer out[c] = dinv[c] * ( g[c] + sum_{col[e]==c} g[row[e]] ) + b
//   g[i] = (h[i] @ W) * dinv[i]
//
// ws (floats): xe[n] dinv[n] g[16n] g2[n] gbuf[8n] uptr[2n] gcur[nb*16]
//              ebufP[nb*CAP] ebuf2P[nb*CAP]   (~66 MB)

#define D_FEAT 128
#define HIDDEN 16
#define TILE 4096
#define CAP 17408u

__device__ inline float bf2f(unsigned short u) {
    union { unsigned x; float f; } t; t.x = ((unsigned)u) << 16; return t.f;
}

__global__ __launch_bounds__(256) void k_init(float* xe, unsigned* gcur, int n, int nb) {
    int t = blockIdx.x * 256 + threadIdx.x;
    if (t < n) xe[t] = 0.f;
    if (t < nb) gcur[t * 16] = (unsigned)t * CAP;
}

// Fused: load row/col/ea; xe wave segmented scan (rows sorted); LDS bucket
// hist; wave-based block scan (2 barriers); claim padded-bucket regions;
// stage bucket-ordered in LDS; coalesced run writes.
__global__ __launch_bounds__(512) void k_sortplace(const int* __restrict__ row,
                                                   const int* __restrict__ col,
                                                   const float* __restrict__ ea,
                                                   float* __restrict__ xe,
                                                   unsigned* __restrict__ gcur,
                                                   unsigned* __restrict__ ebufP,
                                                   int ne, int nb) {
    __shared__ unsigned stage[TILE];
    __shared__ unsigned short sbuck[TILE];
    __shared__ unsigned h[512], base_[512], cursor[512], gb_[512];
    __shared__ unsigned wsum[8];
    int tid = threadIdx.x;
    int lane = tid & 63;
    int w = tid >> 6;
    int tile0 = blockIdx.x * TILE;
    int cnt_t = min(TILE, ne - tile0);
    h[tid] = 0u;
    __syncthreads();
    int rr[8], cc[8];
    float aa[8];
    #pragma unroll
    for (int k = 0; k < 8; ++k) {
        int e = tile0 + tid + k * 512;
        if (e < ne) {
            rr[k] = row[e]; cc[k] = col[e]; aa[k] = ea[e];
            atomicAdd(&h[cc[k] >> 8], 1u);
        } else { rr[k] = -1; cc[k] = 0; aa[k] = 0.f; }
    }
    // xe segmented scan per 64-edge wave window (rows sorted globally).
    #pragma unroll
    for (int k = 0; k < 8; ++k) {
        int r = rr[k];
        float a = aa[k];
        #pragma unroll
        for (int d = 1; d < 64; d <<= 1) {
            float up = __shfl_up(a, d);
            int  rup = __shfl_up(r, d);
            if (lane >= d && rup == r) a += up;
        }
        int rdn = __shfl_down(r, 1);
        bool tail = (lane == 63) || (rdn != r);
        if (r >= 0 && tail) unsafeAtomicAdd(&xe[r], a);
    }
    __syncthreads();
    // Wave-level inclusive scan of h[512] -> exclusive prefix, 2 barriers.
    unsigned hv = h[tid];
    unsigned s = hv;
    #pragma unroll
    for (int d = 1; d < 64; d <<= 1) {
        unsigned u = __shfl_up(s, d);
        if (lane >= d) s += u;
    }
    if (lane == 63) wsum[w] = s;
    __syncthreads();
    unsigned woff = 0;
    #pragma unroll
    for (int i = 0; i < 8; ++i) woff += (i < w) ? wsum[i] : 0u;
    unsigned ex = s + woff - hv;
    base_[tid] = ex;
    cursor[tid] = ex;
    if (tid < nb && hv) gb_[tid] = atomicAdd(&gcur[tid * 16], hv);
    __syncthreads();
    #pragma unroll
    for (int k = 0; k < 8; ++k) {
        if (rr[k] >= 0) {
            int b = cc[k] >> 8;
            unsigned p = atomicAdd(&cursor[b], 1u);
            stage[p] = (((unsigned)(cc[k] & 255)) << 24) | (unsigned)rr[k];
            sbuck[p] = (unsigned short)b;
        }
    }
    __syncthreads();
    for (int t = tid; t < cnt_t; t += 512) {
        unsigned b = sbuck[t];
        unsigned pos = gb_[b] + ((unsigned)t - base_[b]);
        if (pos < (b + 1u) * CAP) ebufP[pos] = stage[t];
    }
}

// Per bucket (1024 threads): exact-col histogram -> uptr{start,end} + dinv,
// scatter into col-sorted ebuf2P. Scan via wave shfl (2 barriers).
__global__ __launch_bounds__(1024) void k_csr2(const unsigned* __restrict__ ebufP,
                                               const unsigned* __restrict__ gcur,
                                               uint2* __restrict__ uptr,
                                               float* __restrict__ dinv,
                                               unsigned* __restrict__ ebuf2P,
                                               int n, int nb) {
    __shared__ unsigned dg[256], cur[256];
    __shared__ unsigned wsum[4];
    int b = blockIdx.x, tid = threadIdx.x;
    int lane = tid & 63;
    if (tid < 256) dg[tid] = 0u;
    __syncthreads();
    unsigned base = (unsigned)b * CAP;
    unsigned m = min(gcur[b * 16] - base, CAP);
    for (unsigned i = tid; i < m; i += 1024) atomicAdd(&dg[ebufP[base + i] >> 24], 1u);
    __syncthreads();
    unsigned dval = 0, s = 0;
    if (tid < 256) {
        dval = dg[tid];
        s = dval;
        #pragma unroll
        for (int d = 1; d < 64; d <<= 1) {
            unsigned u = __shfl_up(s, d);
            if (lane >= d) s += u;
        }
        if (lane == 63) wsum[tid >> 6] = s;
    }
    __syncthreads();
    if (tid < 256) {
        int w = tid >> 6;
        unsigned woff = 0;
        #pragma unroll
        for (int i = 0; i < 4; ++i) woff += (i < w) ? wsum[i] : 0u;
        unsigned ex = s + woff - dval;
        int node = b * 256 + tid;
        if (node < n) {
            uptr[node] = make_uint2(base + ex, base + ex + dval);
            dinv[node] = rsqrtf((float)dval + 1.0f);
        }
        cur[tid] = base + ex;
    }
    __syncthreads();
    unsigned i = tid;
    for (; i + 3072 < m; i += 4096) {
        unsigned pk0 = ebufP[base + i];
        unsigned pk1 = ebufP[base + i + 1024];
        unsigned pk2 = ebufP[base + i + 2048];
        unsigned pk3 = ebufP[base + i + 3072];
        unsigned p0 = atomicAdd(&cur[pk0 >> 24], 1u);
        unsigned p1 = atomicAdd(&cur[pk1 >> 24], 1u);
        unsigned p2 = atomicAdd(&cur[pk2 >> 24], 1u);
        unsigned p3 = atomicAdd(&cur[pk3 >> 24], 1u);
        ebuf2P[p0] = pk0 & 0xFFFFFFu;
        ebuf2P[p1] = pk1 & 0xFFFFFFu;
        ebuf2P[p2] = pk2 & 0xFFFFFFu;
        ebuf2P[p3] = pk3 & 0xFFFFFFu;
    }
    for (; i < m; i += 1024) {
        unsigned pk = ebufP[base + i];
        unsigned p = atomicAdd(&cur[pk >> 24], 1u);
        ebuf2P[p] = pk & 0xFFFFFFu;
    }
}

// g[i][j] = (sum_k x[i][k]*W1[k][j] + xe[i]*W1[128][j]) * dinv[i]
// W transposed in LDS (stride 132) -> b128 weight reads.
// Writes fp32 g (self-term) and bf16 gbuf (gather copy, RNE).
__global__ __launch_bounds__(256) void k_gemm1(const float* __restrict__ x,
                                               const float* __restrict__ xe,
                                               const float* __restrict__ dinv,
                                               const float* __restrict__ W1,
                                               float* __restrict__ g,
                                               unsigned short* __restrict__ gb, int n) {
    __shared__ float WsT[16 * 132];   // WsT[j*132 + k] = W1[k*16 + j], k=0..128
    __shared__ float xs[64 * 132];
    int tid = threadIdx.x;
    for (int idx = tid; idx < 129 * 16; idx += 256) {
        int k = idx >> 4, j = idx & 15;
        WsT[j * 132 + k] = W1[idx];
    }
    int n0 = blockIdx.x * 64;
    const float4* x4 = (const float4*)x;
    for (int idx = tid; idx < 64 * 32; idx += 256) {
        int r = idx >> 5, c = idx & 31;
        float4 v = (n0 + r < n) ? x4[(size_t)(n0 + r) * 32 + c]
                                : make_float4(0.f, 0.f, 0.f, 0.f);
        *(float4*)&xs[r * 132 + c * 4] = v;
    }
    if (tid < 64) {
        int r = tid;
        xs[r * 132 + 128] = (n0 + r < n) ? xe[n0 + r] : 0.f;
    }
    __syncthreads();
    int j  = tid & 15;
    int nb = tid >> 4;
    const float* wrow = &WsT[j * 132];
    for (int rep = 0; rep < 4; ++rep) {
        int nl = nb + (rep << 4);
        int node = n0 + nl;
        const float* xrow = &xs[nl * 132];
        float acc = 0.f;
        #pragma unroll
        for (int k = 0; k < 128; k += 4) {
            float4 xv = *(const float4*)&xrow[k];
            float4 wv = *(const float4*)&wrow[k];
            acc += xv.x * wv.x;
            acc += xv.y * wv.y;
            acc += xv.z * wv.z;
            acc += xv.w * wv.w;
        }
        acc += xrow[128] * wrow[128];
        if (node < n) {
            float v = acc * dinv[node];
            g[(size_t)node * 16 + j] = v;
            union { float f; unsigned u; } cv; cv.f = v;
            unsigned r16 = (cv.u + 0x7FFFu + ((cv.u >> 16) & 1u)) >> 16;
            gb[(size_t)node * 16 + j] = (unsigned short)r16;
        }
    }
}

// Layer-1 agg, packed: 16 lanes/node; lane u=tid&7 owns feature pair
// (2u,2u+1) as one uint load; halves (tid>>3)&1 split even/odd edges;
// shfl_xor(8) combines. Fused epilogue. No LDS, no atomics.
__global__ __launch_bounds__(256) void k_agg16g(const uint2* __restrict__ uptr,
                                                const unsigned* __restrict__ eb2,
                                                const unsigned* __restrict__ gu,
                                                const float* __restrict__ g,
                                                const float* __restrict__ dinv,
                                                const float* __restrict__ b1,
                                                const float* __restrict__ W2,
                                                float* __restrict__ g2, int n) {
    int tid = threadIdx.x;
    int grp = tid >> 4, j16 = tid & 15;
    int u = tid & 7;
    int half = (tid >> 3) & 1;
    int v = blockIdx.x * 16 + grp;
    if (v >= n) return;
    uint2 pr = uptr[v];
    float ax0 = 0.f, ay0 = 0.f, ax1 = 0.f, ay1 = 0.f;
    unsigned q = pr.x + half;
    for (; q + 2 < pr.y; q += 4) {
        unsigned r0 = eb2[q], r1 = eb2[q + 2];
        unsigned w0 = gu[(size_t)r0 * 8 + u];
        unsigned w1 = gu[(size_t)r1 * 8 + u];
        ax0 += bf2f((unsigned short)w0); ay0 += bf2f((unsigned short)(w0 >> 16));
        ax1 += bf2f((unsigned short)w1); ay1 += bf2f((unsigned short)(w1 >> 16));
    }
    if (q < pr.y) {
        unsigned w = gu[(size_t)eb2[q] * 8 + u];
        ax0 += bf2f((unsigned short)w); ay0 += bf2f((unsigned short)(w >> 16));
    }
    float sx = ax0 + ax1, sy = ay0 + ay1;
    sx += __shfl_xor(sx, 8, 16);
    sy += __shfl_xor(sy, 8, 16);
    float di = dinv[v];
    float2 gs = ((const float2*)g)[(size_t)v * 8 + u];
    float2 bb = ((const float2*)b1)[u];
    float2 ww = ((const float2*)W2)[u];
    float vx = fmaxf(di * (gs.x + sx) + bb.x, 0.f);
    float vy = fmaxf(di * (gs.y + sy) + bb.y, 0.f);
    float prd = vx * ww.x + vy * ww.y;
    prd += __shfl_down(prd, 4, 8);
    prd += __shfl_down(prd, 2, 8);
    prd += __shfl_down(prd, 1, 8);
    if (j16 == 0) g2[v] = prd * di;
}

// Layer-2 agg as CSR segmented reduction + fused output.
__global__ __launch_bounds__(256) void k_agg1f(const uint2* __restrict__ uptr,
                                               const unsigned* __restrict__ eb2,
                                               const float* __restrict__ g2,
                                               const float* __restrict__ dinv,
                                               const float* __restrict__ b2,
                                               float* __restrict__ out, int n) {
    int tid = threadIdx.x;
    int grp = tid >> 4, j = tid & 15;
    int v = blockIdx.x * 16 + grp;
    if (v >= n) return;
    uint2 pr = uptr[v];
    float a = 0.f;
    for (unsigned i = pr.x + j; i < pr.y; i += 16) a += g2[eb2[i]];
    a += __shfl_down(a, 8, 16);
    a += __shfl_down(a, 4, 16);
    a += __shfl_down(a, 2, 16);
    a += __shfl_down(a, 1, 16);
    if (j == 0) out[v] = dinv[v] * (g2[v] + a) + b2[0];
}

extern "C" void kernel_launch(void* const* d_in, const int* in_sizes, int n_in,
                              void* d_out, int out_size, void* d_ws, size_t ws_size,
                              hipStream_t stream) {
    const float* x   = (const float*)d_in[0];
    const float* ea  = (const float*)d_in[1];
    const int*   row = (const int*)d_in[2];
    const int*   col = (const int*)d_in[3];
    const float* W1  = (const float*)d_in[4];
    const float* b1  = (const float*)d_in[5];
    const float* W2  = (const float*)d_in[6];
    const float* b2  = (const float*)d_in[7];
    float* out = (float*)d_out;

    int n  = in_sizes[0] / D_FEAT;   // 100000
    int ne = in_sizes[2];            // 6400000
    int nb = (n + 255) >> 8;         // 391 buckets of 256 nodes

    float* ws   = (float*)d_ws;
    float* xe   = ws;                      // n
    float* dinv = ws + (size_t)n;          // n
    float* g    = ws + (size_t)2 * n;      // 16n
    float* g2   = ws + (size_t)18 * n;     // n
    unsigned short* gbuf = (unsigned short*)(ws + (size_t)19 * n);  // 16n ushort = 8n floats
    uint2*    uptr  = (uint2*)(ws + (size_t)27 * n);       // n uint2 = 2n
    unsigned* gcur  = (unsigned*)(ws + (size_t)29 * n);    // nb*16
    unsigned* ebufP  = gcur + (size_t)nb * 16;             // nb*CAP
    unsigned* ebuf2P = ebufP + (size_t)nb * CAP;           // nb*CAP

    dim3 blk(256);
    int g_node = (n + 255) / 256;
    int g_tile = (ne + TILE - 1) / TILE;
    int g_gemm = (n + 63) / 64;
    int g_n16  = (n + 15) / 16;

    k_init<<<g_node, blk, 0, stream>>>(xe, gcur, n, nb);
    k_sortplace<<<g_tile, 512, 0, stream>>>(row, col, ea, xe, gcur, ebufP, ne, nb);
    k_csr2<<<nb, 1024, 0, stream>>>(ebufP, gcur, uptr, dinv, ebuf2P, n, nb);
    k_gemm1<<<g_gemm, blk, 0, stream>>>(x, xe, dinv, W1, g, gbuf, n);
    k_agg16g<<<g_n16, blk, 0, stream>>>(uptr, ebuf2P, (const unsigned*)gbuf, g, dinv, b1, W2, g2, n);
    k_agg1f<<<g_n16, blk, 0, stream>>>(uptr, ebuf2P, g2, dinv, b2, out, n);
}